// Round 11
// baseline (97.942 us; speedup 1.0000x reference)
//
#include <hip/hip_runtime.h>

// ---------------------------------------------------------------------------
// TBasisLayerBase: tensor-ring decompression of an 8192x8192 f32 weight.
//
//   cores[m] (8,4,8) = (bw @ basis) * ra            m = 0..12
//   L = chain(cores[0..5])  -> (8, 4096, 8) ;  R = chain(cores[6..12]) -> (8, 16384, 8)
//   w2d[i,j] = sum_{a,b} L[a,i,b] R[b,j,a]
//   out[row,col] = w2d[ilv6(row>>7,col>>7), ilv7(row&127,col&127)]
//
// GEMM form:  G[m][n] = A2[m][k] * B2t[n][k],  m=(rh,ch) 4096, n=(rl,cl) 16384, k=64
//   out[rh*128+rl][ch*128+cl] = G[rh*64+ch][rl*128+cl]
// Split-bf16 (hi+lo) MFMA keeps f32-level accuracy:
//   G = Ahi*Bhi + Ahi*Blo + Alo*Bhi   (lo*lo term ~2^-18, dropped)
//
// k_out10: block (mb,nbb2) produces TWO consecutive output rows = one
//   contiguous 64-KB extent. r6-grade compute (2 m-tiles/wave, B once/block,
//   dbuf prefetch, bit-identical MFMA order) -> 64-KB LDS image -> single
//   barrier -> each wave streams 16 KB contiguous nt dwordx4 (fill-like
//   DRAM locality). LDS 64 KB -> 2 blocks/CU; store phase of one block
//   overlaps compute phase of the other.
// ---------------------------------------------------------------------------

using bf16x8 = __attribute__((ext_vector_type(8))) short;
using u16x8  = __attribute__((ext_vector_type(8))) unsigned short;
using f32x4  = __attribute__((ext_vector_type(4))) float;
using f32x16 = __attribute__((ext_vector_type(16))) float;

// f32 scratch (float offsets)
#define WS_LA    4096     // 16384 f : (8,256,8)  modes 0-3
#define WS_LB    20480    //  1024 f : (8,16,8)   modes 4-5
#define WS_RA    24576    // 16384 f : (8,256,8)  modes 6-9
#define WS_RB    40960    //  4096 f : (8,64,8)   modes 10-12
// bf16 region (byte offsets from ws base)
#define BOFF_AHI 262144   // [4096][64]  ushort
#define BOFF_ALO 786432
#define BOFF_BHI 1310720  // [16384][64] ushort
#define BOFF_BLO 3407872

__device__ __forceinline__ unsigned short f2bf(float x) {
    unsigned int u = __builtin_bit_cast(unsigned int, x);
    u += 0x7fffu + ((u >> 16) & 1u);          // round-to-nearest-even
    return (unsigned short)(u >> 16);
}
__device__ __forceinline__ float bf2f(unsigned short b) {
    unsigned int u = ((unsigned int)b) << 16;
    return __builtin_bit_cast(float, u);
}

// ---- K1: cores + partial chains. 64 blocks = 4 chains x 16 slices. --------
__global__ void k_chains(const float* __restrict__ bw,
                         const float* __restrict__ basis,
                         const float* __restrict__ ra,
                         float* __restrict__ ws) {
    __shared__ float sCores[13 * 256];
    __shared__ float buf0[4096];
    __shared__ float buf1[4096];
    const int tid   = threadIdx.x;      // 256 threads
    const int chain = blockIdx.x >> 4;  // 0:LA 1:LB 2:RA 3:RB
    const int slice = blockIdx.x & 15;

    const int s0   = (chain == 0) ? 0 : (chain == 1) ? 4 : (chain == 2) ? 6 : 10;
    const int nm   = (chain == 0) ? 4 : (chain == 1) ? 2 : (chain == 2) ? 4 : 3;
    const int wout = (chain == 0) ? WS_LA : (chain == 1) ? WS_LB
                   : (chain == 2) ? WS_RA : WS_RB;

    for (int e = tid; e < 13 * 256; e += 256) {
        int m    = e >> 8;
        int r1   = (e >> 5) & 7;
        int rest = e & 255;
        float s = 0.f;
#pragma unroll
        for (int n = 0; n < 32; ++n)
            s = fmaf(bw[m * 32 + n], basis[n * 256 + rest], s);
        sCores[e] = s * ra[m * 8 + r1];
    }
    __syncthreads();

    const float* src = &sCores[s0 * 256];
    int mcurlog = 2;
    float* dst = buf0;
    for (int step = 1; step < nm; ++step) {
        const float* core = &sCores[(s0 + step) * 256];
        const int moutlog = mcurlog + 2;
        const int mout    = 1 << moutlog;
        const int total   = 64 << moutlog;
        const bool last   = (step == nm - 1);
        const int sz   = total >> 4;
        const int ebeg = last ? slice * sz : 0;
        const int eend = last ? ebeg + sz  : total;
        for (int e = ebeg + tid; e < eend; e += 256) {
            int b  = e & 7;
            int im = (e >> 3) & (mout - 1);
            int a  = e >> (3 + moutlog);
            int i  = im >> 2, mm = im & 3;
            float s = 0.f;
#pragma unroll
            for (int c = 0; c < 8; ++c)
                s = fmaf(src[((a << mcurlog) + i) * 8 + c],
                         core[(c * 4 + mm) * 8 + b], s);
            if (last) ws[wout + e] = s;
            else      dst[e]       = s;
        }
        __syncthreads();
        src = dst;
        dst = (dst == buf0) ? buf1 : buf0;
        mcurlog = moutlog;
    }
}

// bit-interleave: c -> even bit positions, r -> odd bit positions
__device__ __forceinline__ int ilv(int r, int c, int nb) {
    int v = 0;
    for (int t = 0; t < nb; ++t)
        v |= (((c >> t) & 1) << (2 * t)) | (((r >> t) & 1) << (2 * t + 1));
    return v;
}

// ---- K2: build A2 [m][64] and B2t [n][64] (split bf16), 8 k per thread ----
__global__ void k_build(float* __restrict__ ws) {
    int idx = blockIdx.x * 256 + threadIdx.x;   // 32768 + 131072 = 163840
    const float* LA = ws + WS_LA;
    const float* LB = ws + WS_LB;
    const float* RA = ws + WS_RA;
    const float* RB = ws + WS_RB;
    char* wsb = (char*)ws;
    unsigned short* Ahi = (unsigned short*)(wsb + BOFF_AHI);
    unsigned short* Alo = (unsigned short*)(wsb + BOFF_ALO);
    unsigned short* Bhi = (unsigned short*)(wsb + BOFF_BHI);
    unsigned short* Blo = (unsigned short*)(wsb + BOFF_BLO);

    float s[8];
    unsigned short* ph;
    unsigned short* pl;

    if (idx < 32768) {
        int a = idx & 7, m = idx >> 3;
        int ch = m & 63, rh = m >> 6;
        int i  = ilv(rh, ch, 6);
        int iA = i >> 4, iB = i & 15;
        const float* lap = LA + (a * 256 + iA) * 8;
        float la[8];
#pragma unroll
        for (int c = 0; c < 8; ++c) la[c] = lap[c];
#pragma unroll
        for (int b = 0; b < 8; ++b) s[b] = 0.f;
#pragma unroll
        for (int c = 0; c < 8; ++c) {
            const float* lbp = LB + (c * 16 + iB) * 8;
#pragma unroll
            for (int b = 0; b < 8; ++b)
                s[b] = fmaf(la[c], lbp[b], s[b]);
        }
        ph = Ahi + m * 64 + a * 8;
        pl = Alo + m * 64 + a * 8;
    } else {
        int t = idx - 32768;
        int a = t & 7, n = t >> 3;
        int rl = n >> 7, cl = n & 127;
        int j  = ilv(rl, cl, 7);
        int jA = j >> 6, jB = j & 63;
        float rb[8];
#pragma unroll
        for (int c = 0; c < 8; ++c) rb[c] = RB[(c * 64 + jB) * 8 + a];
#pragma unroll
        for (int b = 0; b < 8; ++b) {
            const float* rap = RA + (b * 256 + jA) * 8;
            float acc = 0.f;
#pragma unroll
            for (int c = 0; c < 8; ++c)
                acc = fmaf(rap[c], rb[c], acc);
            s[b] = acc;
        }
        ph = Bhi + n * 64 + a * 8;
        pl = Blo + n * 64 + a * 8;
    }

    u16x8 vh, vl;
#pragma unroll
    for (int b = 0; b < 8; ++b) {
        unsigned short h = f2bf(s[b]);
        vh[b] = h;
        vl[b] = f2bf(s[b] - bf2f(h));
    }
    *(u16x8*)ph = vh;
    *(u16x8*)pl = vl;
}

// ---- K3: 32x32x16 MFMA GEMM -> LDS image -> contiguous nt stream ----------
struct BF { bf16x8 h[4]; bf16x8 l[4]; };

__device__ __forceinline__ void load_half(const unsigned short* __restrict__ base,
                                          int nrow, int hi, bf16x8 (&d)[4]) {
    const unsigned short* p = base + (size_t)nrow * 64 + hi * 8;
#pragma unroll
    for (int kk = 0; kk < 4; ++kk)
        d[kk] = *(const bf16x8*)(p + kk * 16);
}

// One n-tile: 24 MFMA (bit-identical order to r6), results into LDS image.
// nt = local n-tile index 0..7; LDS[rlb*8192 + ch*128 + (nt&3)*32 + l31].
template<bool LN>
__device__ __forceinline__ void tile_iter(
    const unsigned short* __restrict__ Bhi, const unsigned short* __restrict__ Blo,
    float* __restrict__ sOut,
    const bf16x8 (&A0h)[4], const bf16x8 (&A0l)[4],
    const bf16x8 (&A1h)[4], const bf16x8 (&A1l)[4],
    BF& cur, BF& nxt,
    int nrow_next, int nt, int l31, int hi)
{
    if (LN) load_half(Bhi, nrow_next, hi, nxt.h);     // prefetch next Bhi

    f32x16 acc0 = {0,0,0,0,0,0,0,0,0,0,0,0,0,0,0,0};
    f32x16 acc1 = {0,0,0,0,0,0,0,0,0,0,0,0,0,0,0,0};
#pragma unroll
    for (int kk = 0; kk < 4; ++kk) {           // Bh phase: Ah*Bh + Al*Bh
        acc0 = __builtin_amdgcn_mfma_f32_32x32x16_bf16(A0h[kk], cur.h[kk], acc0, 0, 0, 0);
        acc1 = __builtin_amdgcn_mfma_f32_32x32x16_bf16(A1h[kk], cur.h[kk], acc1, 0, 0, 0);
        acc0 = __builtin_amdgcn_mfma_f32_32x32x16_bf16(A0l[kk], cur.h[kk], acc0, 0, 0, 0);
        acc1 = __builtin_amdgcn_mfma_f32_32x32x16_bf16(A1l[kk], cur.h[kk], acc1, 0, 0, 0);
    }
    if (LN) load_half(Blo, nrow_next, hi, nxt.l);     // prefetch next Blo
#pragma unroll
    for (int kk = 0; kk < 4; ++kk) {           // Bl phase: Ah*Bl
        acc0 = __builtin_amdgcn_mfma_f32_32x32x16_bf16(A0h[kk], cur.l[kk], acc0, 0, 0, 0);
        acc1 = __builtin_amdgcn_mfma_f32_32x32x16_bf16(A1h[kk], cur.l[kk], acc1, 0, 0, 0);
    }

    // LDS image: local row rlb = nt>>2 (n-tile*32 >>7), col = ch*128 + (nt&3)*32 + l31
    const int base = (nt >> 2) * 8192 + (nt & 3) * 32 + l31;
#pragma unroll
    for (int r = 0; r < 16; ++r) {
        const int drow = (r & 3) + 8 * (r >> 2);
        const int ch0  = drow + 4 * hi;                // m-tile 0
        sOut[base + (ch0)      * 128] = acc0[r];
        sOut[base + (ch0 + 32) * 128] = acc1[r];       // m-tile 1
    }
}

// grid 4096 = (mb 0..63) x (nbb2 0..63: n [nbb2*256,+256) -> out rows
// {mb*128+nbb2*2, +1} = one contiguous 64-KB extent).
// Wave w: n-tiles {w, w+4}; 2 m-tiles per wave; B read once per block.
// D layout: col=lane&31, row=(reg&3)+8*(reg>>2)+4*(lane>>5)  [verified r4]
__global__ __launch_bounds__(256, 2) void k_out10(const float* __restrict__ ws,
                                                  float* __restrict__ out) {
    __shared__ float sOut[16384];       // 2 output rows, 64 KB

    const char* wsb = (const char*)ws;
    const unsigned short* Ahi = (const unsigned short*)(wsb + BOFF_AHI);
    const unsigned short* Alo = (const unsigned short*)(wsb + BOFF_ALO);
    const unsigned short* Bhi = (const unsigned short*)(wsb + BOFF_BHI);
    const unsigned short* Blo = (const unsigned short*)(wsb + BOFF_BLO);

    const int tid  = threadIdx.x;
    const int lane = tid & 63;
    const int w    = tid >> 6;          // wave 0..3
    const int mb   = blockIdx.x >> 6;   // 0..63
    const int nbb2 = blockIdx.x & 63;   // 0..63
    const int l31  = lane & 31;
    const int hi   = lane >> 5;         // 0/1

    // A fragments: 2 m-tiles x 4 k-steps, hi/lo (row=lane&31, k=kk*16+hi*8+j)
    bf16x8 A0h[4], A0l[4], A1h[4], A1l[4];
    {
        const int m0 = mb * 64 + l31;
        const int m1 = m0 + 32;
#pragma unroll
        for (int kk = 0; kk < 4; ++kk) {
            const int o = kk * 16 + hi * 8;
            A0h[kk] = *(const bf16x8*)(Ahi + m0 * 64 + o);
            A0l[kk] = *(const bf16x8*)(Alo + m0 * 64 + o);
            A1h[kk] = *(const bf16x8*)(Ahi + m1 * 64 + o);
            A1l[kk] = *(const bf16x8*)(Alo + m1 * 64 + o);
        }
    }

    // B rows: n-tile nt -> rows nbb2*256 + nt*32 + l31; wave does nt = w, w+4.
    const int nr0 = nbb2 * 256 + w * 32 + l31;
    BF b0, b1;
    load_half(Bhi, nr0, hi, b0.h);
    load_half(Blo, nr0, hi, b0.l);

    tile_iter<true >(Bhi, Blo, sOut, A0h, A0l, A1h, A1l, b0, b1,
                     nr0 + 128, w,     l31, hi);
    tile_iter<false>(Bhi, Blo, sOut, A0h, A0l, A1h, A1l, b1, b0,
                     0,         w + 4, l31, hi);

    __syncthreads();

    // Stream the 64-KB extent: wave w writes contiguous 16 KB (16 x 1-KB).
    float* __restrict__ obase = out + (((size_t)(mb * 128 + nbb2 * 2)) << 13);
#pragma unroll
    for (int s = 0; s < 16; ++s) {
        const int idx = w * 4096 + s * 256 + lane * 4;
        const f32x4 v = *(const f32x4*)&sOut[idx];
        __builtin_nontemporal_store(v, (f32x4*)(obase + idx));
    }
}

// ---------------------------------------------------------------------------
extern "C" void kernel_launch(void* const* d_in, const int* in_sizes, int n_in,
                              void* d_out, int out_size, void* d_ws, size_t ws_size,
                              hipStream_t stream) {
    const float* bw    = (const float*)d_in[0];   // (13, 32)
    const float* basis = (const float*)d_in[1];   // (32, 8, 4, 8)
    const float* ra    = (const float*)d_in[2];   // (13, 8)
    float* out = (float*)d_out;                   // (8192, 8192) f32
    float* ws  = (float*)d_ws;

    k_chains<<<64,   256, 0, stream>>>(bw, basis, ra, ws);
    k_build <<<640,  256, 0, stream>>>(ws);
    k_out10 <<<4096, 256, 0, stream>>>(ws, out);
}

// Round 12
// 81.222 us; speedup vs baseline: 1.2059x; 1.2059x over previous
//
#include <hip/hip_runtime.h>

// ---------------------------------------------------------------------------
// TBasisLayerBase: tensor-ring decompression of an 8192x8192 f32 weight.
//
//   cores[m] (8,4,8) = (bw @ basis) * ra            m = 0..12
//   L = chain(cores[0..5])  -> (8, 4096, 8) ;  R = chain(cores[6..12]) -> (8, 16384, 8)
//   w2d[i,j] = sum_{a,b} L[a,i,b] R[b,j,a]
//   out[row,col] = w2d[ilv6(row>>7,col>>7), ilv7(row&127,col&127)]
//
// GEMM form:  G[m][n] = A2[m][k] * B2t[n][k],  m=(rh,ch) 4096, n=(rl,cl) 16384, k=64
//   out[rh*128+rl][ch*128+cl] = G[rh*64+ch][rl*128+cl]
// Split-bf16 (hi+lo) MFMA keeps f32-level accuracy:
//   G = Ahi*Bhi + Ahi*Blo + Alo*Bhi   (lo*lo term ~2^-18, dropped)
//
// k_out11: r6 structure (nt dword stores, B double-buffer, 2 m-tiles/wave,
//   occ 3) widened to 64m x 1024n per block (grid 1024, 8 iters) — halves
//   A-fragment prologue overhead and block count; B traffic unchanged;
//   bit-identical MFMA order (absmax must stay 5.6295e14).
// ---------------------------------------------------------------------------

using bf16x8 = __attribute__((ext_vector_type(8))) short;
using u16x8  = __attribute__((ext_vector_type(8))) unsigned short;
using f32x16 = __attribute__((ext_vector_type(16))) float;

// f32 scratch (float offsets)
#define WS_LA    4096     // 16384 f : (8,256,8)  modes 0-3
#define WS_LB    20480    //  1024 f : (8,16,8)   modes 4-5
#define WS_RA    24576    // 16384 f : (8,256,8)  modes 6-9
#define WS_RB    40960    //  4096 f : (8,64,8)   modes 10-12
// bf16 region (byte offsets from ws base)
#define BOFF_AHI 262144   // [4096][64]  ushort
#define BOFF_ALO 786432
#define BOFF_BHI 1310720  // [16384][64] ushort
#define BOFF_BLO 3407872

__device__ __forceinline__ unsigned short f2bf(float x) {
    unsigned int u = __builtin_bit_cast(unsigned int, x);
    u += 0x7fffu + ((u >> 16) & 1u);          // round-to-nearest-even
    return (unsigned short)(u >> 16);
}
__device__ __forceinline__ float bf2f(unsigned short b) {
    unsigned int u = ((unsigned int)b) << 16;
    return __builtin_bit_cast(float, u);
}

// ---- K1: cores + partial chains. 64 blocks = 4 chains x 16 slices. --------
__global__ void k_chains(const float* __restrict__ bw,
                         const float* __restrict__ basis,
                         const float* __restrict__ ra,
                         float* __restrict__ ws) {
    __shared__ float sCores[13 * 256];
    __shared__ float buf0[4096];
    __shared__ float buf1[4096];
    const int tid   = threadIdx.x;      // 256 threads
    const int chain = blockIdx.x >> 4;  // 0:LA 1:LB 2:RA 3:RB
    const int slice = blockIdx.x & 15;

    const int s0   = (chain == 0) ? 0 : (chain == 1) ? 4 : (chain == 2) ? 6 : 10;
    const int nm   = (chain == 0) ? 4 : (chain == 1) ? 2 : (chain == 2) ? 4 : 3;
    const int wout = (chain == 0) ? WS_LA : (chain == 1) ? WS_LB
                   : (chain == 2) ? WS_RA : WS_RB;

    for (int e = tid; e < 13 * 256; e += 256) {
        int m    = e >> 8;
        int r1   = (e >> 5) & 7;
        int rest = e & 255;
        float s = 0.f;
#pragma unroll
        for (int n = 0; n < 32; ++n)
            s = fmaf(bw[m * 32 + n], basis[n * 256 + rest], s);
        sCores[e] = s * ra[m * 8 + r1];
    }
    __syncthreads();

    const float* src = &sCores[s0 * 256];
    int mcurlog = 2;
    float* dst = buf0;
    for (int step = 1; step < nm; ++step) {
        const float* core = &sCores[(s0 + step) * 256];
        const int moutlog = mcurlog + 2;
        const int mout    = 1 << moutlog;
        const int total   = 64 << moutlog;
        const bool last   = (step == nm - 1);
        const int sz   = total >> 4;
        const int ebeg = last ? slice * sz : 0;
        const int eend = last ? ebeg + sz  : total;
        for (int e = ebeg + tid; e < eend; e += 256) {
            int b  = e & 7;
            int im = (e >> 3) & (mout - 1);
            int a  = e >> (3 + moutlog);
            int i  = im >> 2, mm = im & 3;
            float s = 0.f;
#pragma unroll
            for (int c = 0; c < 8; ++c)
                s = fmaf(src[((a << mcurlog) + i) * 8 + c],
                         core[(c * 4 + mm) * 8 + b], s);
            if (last) ws[wout + e] = s;
            else      dst[e]       = s;
        }
        __syncthreads();
        src = dst;
        dst = (dst == buf0) ? buf1 : buf0;
        mcurlog = moutlog;
    }
}

// bit-interleave: c -> even bit positions, r -> odd bit positions
__device__ __forceinline__ int ilv(int r, int c, int nb) {
    int v = 0;
    for (int t = 0; t < nb; ++t)
        v |= (((c >> t) & 1) << (2 * t)) | (((r >> t) & 1) << (2 * t + 1));
    return v;
}

// ---- K2: build A2 [m][64] and B2t [n][64] (split bf16), 8 k per thread ----
__global__ void k_build(float* __restrict__ ws) {
    int idx = blockIdx.x * 256 + threadIdx.x;   // 32768 + 131072 = 163840
    const float* LA = ws + WS_LA;
    const float* LB = ws + WS_LB;
    const float* RA = ws + WS_RA;
    const float* RB = ws + WS_RB;
    char* wsb = (char*)ws;
    unsigned short* Ahi = (unsigned short*)(wsb + BOFF_AHI);
    unsigned short* Alo = (unsigned short*)(wsb + BOFF_ALO);
    unsigned short* Bhi = (unsigned short*)(wsb + BOFF_BHI);
    unsigned short* Blo = (unsigned short*)(wsb + BOFF_BLO);

    float s[8];
    unsigned short* ph;
    unsigned short* pl;

    if (idx < 32768) {
        int a = idx & 7, m = idx >> 3;
        int ch = m & 63, rh = m >> 6;
        int i  = ilv(rh, ch, 6);
        int iA = i >> 4, iB = i & 15;
        const float* lap = LA + (a * 256 + iA) * 8;
        float la[8];
#pragma unroll
        for (int c = 0; c < 8; ++c) la[c] = lap[c];
#pragma unroll
        for (int b = 0; b < 8; ++b) s[b] = 0.f;
#pragma unroll
        for (int c = 0; c < 8; ++c) {
            const float* lbp = LB + (c * 16 + iB) * 8;
#pragma unroll
            for (int b = 0; b < 8; ++b)
                s[b] = fmaf(la[c], lbp[b], s[b]);
        }
        ph = Ahi + m * 64 + a * 8;
        pl = Alo + m * 64 + a * 8;
    } else {
        int t = idx - 32768;
        int a = t & 7, n = t >> 3;
        int rl = n >> 7, cl = n & 127;
        int j  = ilv(rl, cl, 7);
        int jA = j >> 6, jB = j & 63;
        float rb[8];
#pragma unroll
        for (int c = 0; c < 8; ++c) rb[c] = RB[(c * 64 + jB) * 8 + a];
#pragma unroll
        for (int b = 0; b < 8; ++b) {
            const float* rap = RA + (b * 256 + jA) * 8;
            float acc = 0.f;
#pragma unroll
            for (int c = 0; c < 8; ++c)
                acc = fmaf(rap[c], rb[c], acc);
            s[b] = acc;
        }
        ph = Bhi + n * 64 + a * 8;
        pl = Blo + n * 64 + a * 8;
    }

    u16x8 vh, vl;
#pragma unroll
    for (int b = 0; b < 8; ++b) {
        unsigned short h = f2bf(s[b]);
        vh[b] = h;
        vl[b] = f2bf(s[b] - bf2f(h));
    }
    *(u16x8*)ph = vh;
    *(u16x8*)pl = vl;
}

// ---- K3: 32x32x16 MFMA GEMM, nt dword stores, B dbuf, 64m x 1024n ---------
struct BF { bf16x8 h[4]; bf16x8 l[4]; };

__device__ __forceinline__ void load_half(const unsigned short* __restrict__ base,
                                          int nrow, int hi, bf16x8 (&d)[4]) {
    const unsigned short* p = base + (size_t)nrow * 64 + hi * 8;
#pragma unroll
    for (int kk = 0; kk < 4; ++kk)
        d[kk] = *(const bf16x8*)(p + kk * 16);
}

template<int I, bool LN>
__device__ __forceinline__ void tile_iter(
    const unsigned short* __restrict__ Bhi, const unsigned short* __restrict__ Blo,
    float* __restrict__ out,
    const bf16x8 (&A0h)[4], const bf16x8 (&A0l)[4],
    const bf16x8 (&A1h)[4], const bf16x8 (&A1l)[4],
    BF& cur, BF& nxt,
    int mb, int nbb, int w, int l31, int hi)
{
    const int nrown = nbb * 1024 + (I + 1) * 128 + w * 32 + l31;  // next iter's B row
    if (LN) load_half(Bhi, nrown, hi, nxt.h);                     // prefetch Bhi(i+1)

    f32x16 acc0 = {0,0,0,0,0,0,0,0,0,0,0,0,0,0,0,0};
    f32x16 acc1 = {0,0,0,0,0,0,0,0,0,0,0,0,0,0,0,0};
#pragma unroll
    for (int kk = 0; kk < 4; ++kk) {           // Bh phase: Ah*Bh + Al*Bh
        acc0 = __builtin_amdgcn_mfma_f32_32x32x16_bf16(A0h[kk], cur.h[kk], acc0, 0, 0, 0);
        acc1 = __builtin_amdgcn_mfma_f32_32x32x16_bf16(A1h[kk], cur.h[kk], acc1, 0, 0, 0);
        acc0 = __builtin_amdgcn_mfma_f32_32x32x16_bf16(A0l[kk], cur.h[kk], acc0, 0, 0, 0);
        acc1 = __builtin_amdgcn_mfma_f32_32x32x16_bf16(A1l[kk], cur.h[kk], acc1, 0, 0, 0);
    }
    if (LN) load_half(Blo, nrown, hi, nxt.l);                     // prefetch Blo(i+1)
#pragma unroll
    for (int kk = 0; kk < 4; ++kk) {           // Bl phase: Ah*Bl
        acc0 = __builtin_amdgcn_mfma_f32_32x32x16_bf16(A0h[kk], cur.l[kk], acc0, 0, 0, 0);
        acc1 = __builtin_amdgcn_mfma_f32_32x32x16_bf16(A1h[kk], cur.l[kk], acc1, 0, 0, 0);
    }

    // store: out row = mb*128 + nbb*8 + I; col = ch*128 + w*32 + l31,
    //        ch = drow + 4*hi (+32 for m-tile 1), drow = (r&3)+8*(r>>2)
    const int rl = nbb * 8 + I;
    float* __restrict__ obase =
        out + (((size_t)(mb * 128 + rl)) << 13) + w * 32 + l31 + (size_t)hi * 512;
    float* __restrict__ obase2 = obase + 32 * 128;
#pragma unroll
    for (int r = 0; r < 16; ++r) {
        const int drow = (r & 3) + 8 * (r >> 2);
        __builtin_nontemporal_store(acc0[r], obase  + (size_t)drow * 128);
        __builtin_nontemporal_store(acc1[r], obase2 + (size_t)drow * 128);
    }
}

// grid 1024 = (mb 0..63: m rows [mb*64,+64)) x (nbb 0..15: n [nbb*1024,+1024)).
// bid%8 = nbb%8 -> same-nbb blocks share an XCD (B slice L2-resident).
// D layout: col=lane&31, row=(reg&3)+8*(reg>>2)+4*(lane>>5)  [verified r4]
__global__ __launch_bounds__(256, 3) void k_out11(const float* __restrict__ ws,
                                                  float* __restrict__ out) {
    const char* wsb = (const char*)ws;
    const unsigned short* Ahi = (const unsigned short*)(wsb + BOFF_AHI);
    const unsigned short* Alo = (const unsigned short*)(wsb + BOFF_ALO);
    const unsigned short* Bhi = (const unsigned short*)(wsb + BOFF_BHI);
    const unsigned short* Blo = (const unsigned short*)(wsb + BOFF_BLO);

    const int tid  = threadIdx.x;
    const int lane = tid & 63;
    const int w    = tid >> 6;          // wave 0..3
    const int mb   = blockIdx.x >> 4;   // 0..63
    const int nbb  = blockIdx.x & 15;   // 0..15
    const int l31  = lane & 31;
    const int hi   = lane >> 5;         // 0/1

    // A fragments: 2 m-tiles x 4 k-steps, hi/lo (row=lane&31, k=kk*16+hi*8+j)
    bf16x8 A0h[4], A0l[4], A1h[4], A1l[4];
    {
        const int m0 = mb * 64 + l31;
        const int m1 = m0 + 32;
#pragma unroll
        for (int kk = 0; kk < 4; ++kk) {
            const int o = kk * 16 + hi * 8;
            A0h[kk] = *(const bf16x8*)(Ahi + m0 * 64 + o);
            A0l[kk] = *(const bf16x8*)(Alo + m0 * 64 + o);
            A1h[kk] = *(const bf16x8*)(Ahi + m1 * 64 + o);
            A1l[kk] = *(const bf16x8*)(Alo + m1 * 64 + o);
        }
    }

    BF b0, b1;
    {
        const int nrow0 = nbb * 1024 + w * 32 + l31;   // i=0
        load_half(Bhi, nrow0, hi, b0.h);
        load_half(Blo, nrow0, hi, b0.l);
    }

    tile_iter<0, true >(Bhi, Blo, out, A0h, A0l, A1h, A1l, b0, b1, mb, nbb, w, l31, hi);
    tile_iter<1, true >(Bhi, Blo, out, A0h, A0l, A1h, A1l, b1, b0, mb, nbb, w, l31, hi);
    tile_iter<2, true >(Bhi, Blo, out, A0h, A0l, A1h, A1l, b0, b1, mb, nbb, w, l31, hi);
    tile_iter<3, true >(Bhi, Blo, out, A0h, A0l, A1h, A1l, b1, b0, mb, nbb, w, l31, hi);
    tile_iter<4, true >(Bhi, Blo, out, A0h, A0l, A1h, A1l, b0, b1, mb, nbb, w, l31, hi);
    tile_iter<5, true >(Bhi, Blo, out, A0h, A0l, A1h, A1l, b1, b0, mb, nbb, w, l31, hi);
    tile_iter<6, true >(Bhi, Blo, out, A0h, A0l, A1h, A1l, b0, b1, mb, nbb, w, l31, hi);
    tile_iter<7, false>(Bhi, Blo, out, A0h, A0l, A1h, A1l, b1, b0, mb, nbb, w, l31, hi);
}

// ---------------------------------------------------------------------------
extern "C" void kernel_launch(void* const* d_in, const int* in_sizes, int n_in,
                              void* d_out, int out_size, void* d_ws, size_t ws_size,
                              hipStream_t stream) {
    const float* bw    = (const float*)d_in[0];   // (13, 32)
    const float* basis = (const float*)d_in[1];   // (32, 8, 4, 8)
    const float* ra    = (const float*)d_in[2];   // (13, 8)
    float* out = (float*)d_out;                   // (8192, 8192) f32
    float* ws  = (float*)d_ws;

    k_chains<<<64,   256, 0, stream>>>(bw, basis, ra, ws);
    k_build <<<640,  256, 0, stream>>>(ws);
    k_out11 <<<1024, 256, 0, stream>>>(ws, out);
}

// Round 13
// 81.085 us; speedup vs baseline: 1.2079x; 1.0017x over previous
//
#include <hip/hip_runtime.h>

// ---------------------------------------------------------------------------
// TBasisLayerBase: tensor-ring decompression of an 8192x8192 f32 weight.
//
//   cores[m] (8,4,8) = (bw @ basis) * ra            m = 0..12
//   L = chain(cores[0..5])  -> (8, 4096, 8) ;  R = chain(cores[6..12]) -> (8, 16384, 8)
//   w2d[i,j] = sum_{a,b} L[a,i,b] R[b,j,a]
//   out[row,col] = w2d[ilv6(row>>7,col>>7), ilv7(row&127,col&127)]
//
// GEMM form:  G[m][n] = A2[m][k] * B2t[n][k],  m=(rh,ch) 4096, n=(rl,cl) 16384, k=64
//   out[rh*128+rl][ch*128+cl] = G[rh*64+ch][rl*128+cl]
// Split-bf16 (hi+lo) MFMA keeps f32-level accuracy:
//   G = Ahi*Bhi + Ahi*Blo + Alo*Bhi   (lo*lo term ~2^-18, dropped)
//
// k_out12: r6 compute engine (2 m-tiles/wave, B dbuf, bit-identical MFMA
//   order, occ 3, grid 2048) + 32-KB one-row LDS stage + 4 fine phases.
//   Store phase = contiguous nt dwordx4 streams (1 KB/instr, fill-like) —
//   the one store pattern never paired with good compute (r11 tested it at
//   occ 2 / coarse phases and lost to overlap, not to the mechanism).
// ---------------------------------------------------------------------------

using bf16x8 = __attribute__((ext_vector_type(8))) short;
using u16x8  = __attribute__((ext_vector_type(8))) unsigned short;
using f32x4  = __attribute__((ext_vector_type(4))) float;
using f32x16 = __attribute__((ext_vector_type(16))) float;

// f32 scratch (float offsets)
#define WS_LA    4096     // 16384 f : (8,256,8)  modes 0-3
#define WS_LB    20480    //  1024 f : (8,16,8)   modes 4-5
#define WS_RA    24576    // 16384 f : (8,256,8)  modes 6-9
#define WS_RB    40960    //  4096 f : (8,64,8)   modes 10-12
// bf16 region (byte offsets from ws base)
#define BOFF_AHI 262144   // [4096][64]  ushort
#define BOFF_ALO 786432
#define BOFF_BHI 1310720  // [16384][64] ushort
#define BOFF_BLO 3407872

__device__ __forceinline__ unsigned short f2bf(float x) {
    unsigned int u = __builtin_bit_cast(unsigned int, x);
    u += 0x7fffu + ((u >> 16) & 1u);          // round-to-nearest-even
    return (unsigned short)(u >> 16);
}
__device__ __forceinline__ float bf2f(unsigned short b) {
    unsigned int u = ((unsigned int)b) << 16;
    return __builtin_bit_cast(float, u);
}

// ---- K1: cores + partial chains. 64 blocks = 4 chains x 16 slices. --------
__global__ void k_chains(const float* __restrict__ bw,
                         const float* __restrict__ basis,
                         const float* __restrict__ ra,
                         float* __restrict__ ws) {
    __shared__ float sCores[13 * 256];
    __shared__ float buf0[4096];
    __shared__ float buf1[4096];
    const int tid   = threadIdx.x;      // 256 threads
    const int chain = blockIdx.x >> 4;  // 0:LA 1:LB 2:RA 3:RB
    const int slice = blockIdx.x & 15;

    const int s0   = (chain == 0) ? 0 : (chain == 1) ? 4 : (chain == 2) ? 6 : 10;
    const int nm   = (chain == 0) ? 4 : (chain == 1) ? 2 : (chain == 2) ? 4 : 3;
    const int wout = (chain == 0) ? WS_LA : (chain == 1) ? WS_LB
                   : (chain == 2) ? WS_RA : WS_RB;

    for (int e = tid; e < 13 * 256; e += 256) {
        int m    = e >> 8;
        int r1   = (e >> 5) & 7;
        int rest = e & 255;
        float s = 0.f;
#pragma unroll
        for (int n = 0; n < 32; ++n)
            s = fmaf(bw[m * 32 + n], basis[n * 256 + rest], s);
        sCores[e] = s * ra[m * 8 + r1];
    }
    __syncthreads();

    const float* src = &sCores[s0 * 256];
    int mcurlog = 2;
    float* dst = buf0;
    for (int step = 1; step < nm; ++step) {
        const float* core = &sCores[(s0 + step) * 256];
        const int moutlog = mcurlog + 2;
        const int mout    = 1 << moutlog;
        const int total   = 64 << moutlog;
        const bool last   = (step == nm - 1);
        const int sz   = total >> 4;
        const int ebeg = last ? slice * sz : 0;
        const int eend = last ? ebeg + sz  : total;
        for (int e = ebeg + tid; e < eend; e += 256) {
            int b  = e & 7;
            int im = (e >> 3) & (mout - 1);
            int a  = e >> (3 + moutlog);
            int i  = im >> 2, mm = im & 3;
            float s = 0.f;
#pragma unroll
            for (int c = 0; c < 8; ++c)
                s = fmaf(src[((a << mcurlog) + i) * 8 + c],
                         core[(c * 4 + mm) * 8 + b], s);
            if (last) ws[wout + e] = s;
            else      dst[e]       = s;
        }
        __syncthreads();
        src = dst;
        dst = (dst == buf0) ? buf1 : buf0;
        mcurlog = moutlog;
    }
}

// bit-interleave: c -> even bit positions, r -> odd bit positions
__device__ __forceinline__ int ilv(int r, int c, int nb) {
    int v = 0;
    for (int t = 0; t < nb; ++t)
        v |= (((c >> t) & 1) << (2 * t)) | (((r >> t) & 1) << (2 * t + 1));
    return v;
}

// ---- K2: build A2 [m][64] and B2t [n][64] (split bf16), 8 k per thread ----
__global__ void k_build(float* __restrict__ ws) {
    int idx = blockIdx.x * 256 + threadIdx.x;   // 32768 + 131072 = 163840
    const float* LA = ws + WS_LA;
    const float* LB = ws + WS_LB;
    const float* RA = ws + WS_RA;
    const float* RB = ws + WS_RB;
    char* wsb = (char*)ws;
    unsigned short* Ahi = (unsigned short*)(wsb + BOFF_AHI);
    unsigned short* Alo = (unsigned short*)(wsb + BOFF_ALO);
    unsigned short* Bhi = (unsigned short*)(wsb + BOFF_BHI);
    unsigned short* Blo = (unsigned short*)(wsb + BOFF_BLO);

    float s[8];
    unsigned short* ph;
    unsigned short* pl;

    if (idx < 32768) {
        int a = idx & 7, m = idx >> 3;
        int ch = m & 63, rh = m >> 6;
        int i  = ilv(rh, ch, 6);
        int iA = i >> 4, iB = i & 15;
        const float* lap = LA + (a * 256 + iA) * 8;
        float la[8];
#pragma unroll
        for (int c = 0; c < 8; ++c) la[c] = lap[c];
#pragma unroll
        for (int b = 0; b < 8; ++b) s[b] = 0.f;
#pragma unroll
        for (int c = 0; c < 8; ++c) {
            const float* lbp = LB + (c * 16 + iB) * 8;
#pragma unroll
            for (int b = 0; b < 8; ++b)
                s[b] = fmaf(la[c], lbp[b], s[b]);
        }
        ph = Ahi + m * 64 + a * 8;
        pl = Alo + m * 64 + a * 8;
    } else {
        int t = idx - 32768;
        int a = t & 7, n = t >> 3;
        int rl = n >> 7, cl = n & 127;
        int j  = ilv(rl, cl, 7);
        int jA = j >> 6, jB = j & 63;
        float rb[8];
#pragma unroll
        for (int c = 0; c < 8; ++c) rb[c] = RB[(c * 64 + jB) * 8 + a];
#pragma unroll
        for (int b = 0; b < 8; ++b) {
            const float* rap = RA + (b * 256 + jA) * 8;
            float acc = 0.f;
#pragma unroll
            for (int c = 0; c < 8; ++c)
                acc = fmaf(rap[c], rb[c], acc);
            s[b] = acc;
        }
        ph = Bhi + n * 64 + a * 8;
        pl = Blo + n * 64 + a * 8;
    }

    u16x8 vh, vl;
#pragma unroll
    for (int b = 0; b < 8; ++b) {
        unsigned short h = f2bf(s[b]);
        vh[b] = h;
        vl[b] = f2bf(s[b] - bf2f(h));
    }
    *(u16x8*)ph = vh;
    *(u16x8*)pl = vl;
}

// ---- K3: MFMA GEMM, 4 row-phases: LDS row image -> contiguous nt stream ---
struct BF { bf16x8 h[4]; bf16x8 l[4]; };

__device__ __forceinline__ void load_half(const unsigned short* __restrict__ base,
                                          int nrow, int hi, bf16x8 (&d)[4]) {
    const unsigned short* p = base + (size_t)nrow * 64 + hi * 8;
#pragma unroll
    for (int kk = 0; kk < 4; ++kk)
        d[kk] = *(const bf16x8*)(p + kk * 16);
}

// Phase I: compute one output row (wave w = n-tile I*4+w, 2 m-tiles),
// stage to 32-KB LDS row image, barrier, stream contiguous nt dwordx4.
// MFMA order bit-identical to r6 (absmax regression check).
template<int I, bool LN>
__device__ __forceinline__ void row_iter(
    const unsigned short* __restrict__ Bhi, const unsigned short* __restrict__ Blo,
    float* __restrict__ sOut, float* __restrict__ out,
    const bf16x8 (&A0h)[4], const bf16x8 (&A0l)[4],
    const bf16x8 (&A1h)[4], const bf16x8 (&A1l)[4],
    BF& cur, BF& nxt,
    int mb, int nbb, int w, int tid, int l31, int hi)
{
    const int nrown = nbb * 512 + (I + 1) * 128 + w * 32 + l31;   // next phase's B row
    if (LN) load_half(Bhi, nrown, hi, nxt.h);                     // prefetch Bhi

    f32x16 acc0 = {0,0,0,0,0,0,0,0,0,0,0,0,0,0,0,0};
    f32x16 acc1 = {0,0,0,0,0,0,0,0,0,0,0,0,0,0,0,0};
#pragma unroll
    for (int kk = 0; kk < 4; ++kk) {           // Bh phase: Ah*Bh + Al*Bh
        acc0 = __builtin_amdgcn_mfma_f32_32x32x16_bf16(A0h[kk], cur.h[kk], acc0, 0, 0, 0);
        acc1 = __builtin_amdgcn_mfma_f32_32x32x16_bf16(A1h[kk], cur.h[kk], acc1, 0, 0, 0);
        acc0 = __builtin_amdgcn_mfma_f32_32x32x16_bf16(A0l[kk], cur.h[kk], acc0, 0, 0, 0);
        acc1 = __builtin_amdgcn_mfma_f32_32x32x16_bf16(A1l[kk], cur.h[kk], acc1, 0, 0, 0);
    }
    if (LN) load_half(Blo, nrown, hi, nxt.l);                     // prefetch Blo
#pragma unroll
    for (int kk = 0; kk < 4; ++kk) {           // Bl phase: Ah*Bl
        acc0 = __builtin_amdgcn_mfma_f32_32x32x16_bf16(A0h[kk], cur.l[kk], acc0, 0, 0, 0);
        acc1 = __builtin_amdgcn_mfma_f32_32x32x16_bf16(A1h[kk], cur.l[kk], acc1, 0, 0, 0);
    }

    // LDS row image: image[ch*128 + cl], cl = w*32 + l31, ch = drow+4hi (+32)
    const int base = w * 32 + l31;
#pragma unroll
    for (int r = 0; r < 16; ++r) {
        const int drow = (r & 3) + 8 * (r >> 2);
        const int ch0  = drow + 4 * hi;
        sOut[(ch0)      * 128 + base] = acc0[r];
        sOut[(ch0 + 32) * 128 + base] = acc1[r];
    }
    __syncthreads();

    // contiguous stream: wave w writes [w*2048, +2048) of the 8192-f row
    float* __restrict__ obase = out + (((size_t)(mb * 128 + nbb * 4 + I)) << 13);
    const int lane4 = (tid & 63) * 4;
#pragma unroll
    for (int s = 0; s < 8; ++s) {
        const int idx = w * 2048 + s * 256 + lane4;
        const f32x4 v = *(const f32x4*)&sOut[idx];
        __builtin_nontemporal_store(v, (f32x4*)(obase + idx));
    }
    __syncthreads();
}

// grid 2048 = (mb 0..63: m rows [mb*64,+64)) x (nbb 0..31: n [nbb*512,+512)).
// 4 phases; phase I -> out row mb*128 + nbb*4 + I.
// D layout: col=lane&31, row=(reg&3)+8*(reg>>2)+4*(lane>>5)  [verified r4]
__global__ __launch_bounds__(256, 3) void k_out12(const float* __restrict__ ws,
                                                  float* __restrict__ out) {
    __shared__ float sOut[8192];        // one output row, 32 KB

    const char* wsb = (const char*)ws;
    const unsigned short* Ahi = (const unsigned short*)(wsb + BOFF_AHI);
    const unsigned short* Alo = (const unsigned short*)(wsb + BOFF_ALO);
    const unsigned short* Bhi = (const unsigned short*)(wsb + BOFF_BHI);
    const unsigned short* Blo = (const unsigned short*)(wsb + BOFF_BLO);

    const int tid  = threadIdx.x;
    const int lane = tid & 63;
    const int w    = tid >> 6;          // wave 0..3
    const int mb   = blockIdx.x >> 5;   // 0..63
    const int nbb  = blockIdx.x & 31;   // 0..31
    const int l31  = lane & 31;
    const int hi   = lane >> 5;         // 0/1

    // A fragments: 2 m-tiles x 4 k-steps, hi/lo (row=lane&31, k=kk*16+hi*8+j)
    bf16x8 A0h[4], A0l[4], A1h[4], A1l[4];
    {
        const int m0 = mb * 64 + l31;
        const int m1 = m0 + 32;
#pragma unroll
        for (int kk = 0; kk < 4; ++kk) {
            const int o = kk * 16 + hi * 8;
            A0h[kk] = *(const bf16x8*)(Ahi + m0 * 64 + o);
            A0l[kk] = *(const bf16x8*)(Alo + m0 * 64 + o);
            A1h[kk] = *(const bf16x8*)(Ahi + m1 * 64 + o);
            A1l[kk] = *(const bf16x8*)(Alo + m1 * 64 + o);
        }
    }

    BF b0, b1;
    {
        const int nrow0 = nbb * 512 + w * 32 + l31;   // phase 0
        load_half(Bhi, nrow0, hi, b0.h);
        load_half(Blo, nrow0, hi, b0.l);
    }

    row_iter<0, true >(Bhi, Blo, sOut, out, A0h, A0l, A1h, A1l, b0, b1, mb, nbb, w, tid, l31, hi);
    row_iter<1, true >(Bhi, Blo, sOut, out, A0h, A0l, A1h, A1l, b1, b0, mb, nbb, w, tid, l31, hi);
    row_iter<2, true >(Bhi, Blo, sOut, out, A0h, A0l, A1h, A1l, b0, b1, mb, nbb, w, tid, l31, hi);
    row_iter<3, false>(Bhi, Blo, sOut, out, A0h, A0l, A1h, A1l, b1, b0, mb, nbb, w, tid, l31, hi);
}

// ---------------------------------------------------------------------------
extern "C" void kernel_launch(void* const* d_in, const int* in_sizes, int n_in,
                              void* d_out, int out_size, void* d_ws, size_t ws_size,
                              hipStream_t stream) {
    const float* bw    = (const float*)d_in[0];   // (13, 32)
    const float* basis = (const float*)d_in[1];   // (32, 8, 4, 8)
    const float* ra    = (const float*)d_in[2];   // (13, 8)
    float* out = (float*)d_out;                   // (8192, 8192) f32
    float* ws  = (float*)d_ws;

    k_chains<<<64,   256, 0, stream>>>(bw, basis, ra, ws);
    k_build <<<640,  256, 0, stream>>>(ws);
    k_out12 <<<2048, 256, 0, stream>>>(ws, out);
}

// Round 14
// 78.662 us; speedup vs baseline: 1.2451x; 1.0308x over previous
//
#include <hip/hip_runtime.h>

// ---------------------------------------------------------------------------
// TBasisLayerBase: tensor-ring decompression of an 8192x8192 f32 weight.
//
//   cores[m] (8,4,8) = (bw @ basis) * ra            m = 0..12
//   L = chain(cores[0..5])  -> (8, 4096, 8) ;  R = chain(cores[6..12]) -> (8, 16384, 8)
//   w2d[i,j] = sum_{a,b} L[a,i,b] R[b,j,a]
//   out[row,col] = w2d[ilv6(row>>7,col>>7), ilv7(row&127,col&127)]
//
// GEMM form:  G[m][n] = A2[m][k] * B2t[n][k],  m=(rh,ch) 4096, n=(rl,cl) 16384, k=64
//   out[rh*128+rl][ch*128+cl] = G[rh*64+ch][rl*128+cl]
// Split-bf16 (hi+lo) MFMA keeps f32-level accuracy:
//   G = Ahi*Bhi + Ahi*Blo + Alo*Bhi   (lo*lo term ~2^-18, dropped)
//
// FINAL (= round-6 best, 79.2 us): k_out5 32x32x16 MFMA, 64m x 512n per
// block, nontemporal dword stores, explicit B double-buffer. Ablation ledger
// (r7-r13): payload width, in-flight bytes, wave lifecycle, VGPR pressure,
// DRAM stream locality, LDS-staged contiguous streams — all neutral or
// regressions. ~70 us k_out vs 39 us pure-fill write floor is the structural
// cost of MFMA+read+commit on this memory system; practical roofline.
// ---------------------------------------------------------------------------

using bf16x8 = __attribute__((ext_vector_type(8))) short;
using u16x8  = __attribute__((ext_vector_type(8))) unsigned short;
using f32x16 = __attribute__((ext_vector_type(16))) float;

// f32 scratch (float offsets)
#define WS_LA    4096     // 16384 f : (8,256,8)  modes 0-3
#define WS_LB    20480    //  1024 f : (8,16,8)   modes 4-5
#define WS_RA    24576    // 16384 f : (8,256,8)  modes 6-9
#define WS_RB    40960    //  4096 f : (8,64,8)   modes 10-12
// bf16 region (byte offsets from ws base)
#define BOFF_AHI 262144   // [4096][64]  ushort
#define BOFF_ALO 786432
#define BOFF_BHI 1310720  // [16384][64] ushort
#define BOFF_BLO 3407872

__device__ __forceinline__ unsigned short f2bf(float x) {
    unsigned int u = __builtin_bit_cast(unsigned int, x);
    u += 0x7fffu + ((u >> 16) & 1u);          // round-to-nearest-even
    return (unsigned short)(u >> 16);
}
__device__ __forceinline__ float bf2f(unsigned short b) {
    unsigned int u = ((unsigned int)b) << 16;
    return __builtin_bit_cast(float, u);
}

// ---- K1: cores + partial chains. 64 blocks = 4 chains x 16 slices. --------
__global__ void k_chains(const float* __restrict__ bw,
                         const float* __restrict__ basis,
                         const float* __restrict__ ra,
                         float* __restrict__ ws) {
    __shared__ float sCores[13 * 256];
    __shared__ float buf0[4096];
    __shared__ float buf1[4096];
    const int tid   = threadIdx.x;      // 256 threads
    const int chain = blockIdx.x >> 4;  // 0:LA 1:LB 2:RA 3:RB
    const int slice = blockIdx.x & 15;

    const int s0   = (chain == 0) ? 0 : (chain == 1) ? 4 : (chain == 2) ? 6 : 10;
    const int nm   = (chain == 0) ? 4 : (chain == 1) ? 2 : (chain == 2) ? 4 : 3;
    const int wout = (chain == 0) ? WS_LA : (chain == 1) ? WS_LB
                   : (chain == 2) ? WS_RA : WS_RB;

    for (int e = tid; e < 13 * 256; e += 256) {
        int m    = e >> 8;
        int r1   = (e >> 5) & 7;
        int rest = e & 255;
        float s = 0.f;
#pragma unroll
        for (int n = 0; n < 32; ++n)
            s = fmaf(bw[m * 32 + n], basis[n * 256 + rest], s);
        sCores[e] = s * ra[m * 8 + r1];
    }
    __syncthreads();

    const float* src = &sCores[s0 * 256];
    int mcurlog = 2;
    float* dst = buf0;
    for (int step = 1; step < nm; ++step) {
        const float* core = &sCores[(s0 + step) * 256];
        const int moutlog = mcurlog + 2;
        const int mout    = 1 << moutlog;
        const int total   = 64 << moutlog;
        const bool last   = (step == nm - 1);
        const int sz   = total >> 4;
        const int ebeg = last ? slice * sz : 0;
        const int eend = last ? ebeg + sz  : total;
        for (int e = ebeg + tid; e < eend; e += 256) {
            int b  = e & 7;
            int im = (e >> 3) & (mout - 1);
            int a  = e >> (3 + moutlog);
            int i  = im >> 2, mm = im & 3;
            float s = 0.f;
#pragma unroll
            for (int c = 0; c < 8; ++c)
                s = fmaf(src[((a << mcurlog) + i) * 8 + c],
                         core[(c * 4 + mm) * 8 + b], s);
            if (last) ws[wout + e] = s;
            else      dst[e]       = s;
        }
        __syncthreads();
        src = dst;
        dst = (dst == buf0) ? buf1 : buf0;
        mcurlog = moutlog;
    }
}

// bit-interleave: c -> even bit positions, r -> odd bit positions
__device__ __forceinline__ int ilv(int r, int c, int nb) {
    int v = 0;
    for (int t = 0; t < nb; ++t)
        v |= (((c >> t) & 1) << (2 * t)) | (((r >> t) & 1) << (2 * t + 1));
    return v;
}

// ---- K2: build A2 [m][64] and B2t [n][64] (split bf16), 8 k per thread ----
__global__ void k_build(float* __restrict__ ws) {
    int idx = blockIdx.x * 256 + threadIdx.x;   // 32768 + 131072 = 163840
    const float* LA = ws + WS_LA;
    const float* LB = ws + WS_LB;
    const float* RA = ws + WS_RA;
    const float* RB = ws + WS_RB;
    char* wsb = (char*)ws;
    unsigned short* Ahi = (unsigned short*)(wsb + BOFF_AHI);
    unsigned short* Alo = (unsigned short*)(wsb + BOFF_ALO);
    unsigned short* Bhi = (unsigned short*)(wsb + BOFF_BHI);
    unsigned short* Blo = (unsigned short*)(wsb + BOFF_BLO);

    float s[8];
    unsigned short* ph;
    unsigned short* pl;

    if (idx < 32768) {
        int a = idx & 7, m = idx >> 3;
        int ch = m & 63, rh = m >> 6;
        int i  = ilv(rh, ch, 6);
        int iA = i >> 4, iB = i & 15;
        const float* lap = LA + (a * 256 + iA) * 8;
        float la[8];
#pragma unroll
        for (int c = 0; c < 8; ++c) la[c] = lap[c];
#pragma unroll
        for (int b = 0; b < 8; ++b) s[b] = 0.f;
#pragma unroll
        for (int c = 0; c < 8; ++c) {
            const float* lbp = LB + (c * 16 + iB) * 8;
#pragma unroll
            for (int b = 0; b < 8; ++b)
                s[b] = fmaf(la[c], lbp[b], s[b]);
        }
        ph = Ahi + m * 64 + a * 8;
        pl = Alo + m * 64 + a * 8;
    } else {
        int t = idx - 32768;
        int a = t & 7, n = t >> 3;
        int rl = n >> 7, cl = n & 127;
        int j  = ilv(rl, cl, 7);
        int jA = j >> 6, jB = j & 63;
        float rb[8];
#pragma unroll
        for (int c = 0; c < 8; ++c) rb[c] = RB[(c * 64 + jB) * 8 + a];
#pragma unroll
        for (int b = 0; b < 8; ++b) {
            const float* rap = RA + (b * 256 + jA) * 8;
            float acc = 0.f;
#pragma unroll
            for (int c = 0; c < 8; ++c)
                acc = fmaf(rap[c], rb[c], acc);
            s[b] = acc;
        }
        ph = Bhi + n * 64 + a * 8;
        pl = Blo + n * 64 + a * 8;
    }

    u16x8 vh, vl;
#pragma unroll
    for (int b = 0; b < 8; ++b) {
        unsigned short h = f2bf(s[b]);
        vh[b] = h;
        vl[b] = f2bf(s[b] - bf2f(h));
    }
    *(u16x8*)ph = vh;
    *(u16x8*)pl = vl;
}

// ---- K3: 32x32x16 MFMA GEMM, nt stores, explicit B double-buffer ----------
struct BF { bf16x8 h[4]; bf16x8 l[4]; };

__device__ __forceinline__ void load_half(const unsigned short* __restrict__ base,
                                          int nrow, int hi, bf16x8 (&d)[4]) {
    const unsigned short* p = base + (size_t)nrow * 64 + hi * 8;
#pragma unroll
    for (int kk = 0; kk < 4; ++kk)
        d[kk] = *(const bf16x8*)(p + kk * 16);
}

template<int I, bool LN>
__device__ __forceinline__ void tile_iter(
    const unsigned short* __restrict__ Bhi, const unsigned short* __restrict__ Blo,
    float* __restrict__ out,
    const bf16x8 (&A0h)[4], const bf16x8 (&A0l)[4],
    const bf16x8 (&A1h)[4], const bf16x8 (&A1l)[4],
    BF& cur, BF& nxt,
    int mb, int nbb, int w, int l31, int hi)
{
    const int nrown = nbb * 512 + (I + 1) * 128 + w * 32 + l31;   // next iter's B row
    if (LN) load_half(Bhi, nrown, hi, nxt.h);                     // prefetch Bhi(i+1)

    f32x16 acc0 = {0,0,0,0,0,0,0,0,0,0,0,0,0,0,0,0};
    f32x16 acc1 = {0,0,0,0,0,0,0,0,0,0,0,0,0,0,0,0};
#pragma unroll
    for (int kk = 0; kk < 4; ++kk) {           // Bh phase: Ah*Bh + Al*Bh
        acc0 = __builtin_amdgcn_mfma_f32_32x32x16_bf16(A0h[kk], cur.h[kk], acc0, 0, 0, 0);
        acc1 = __builtin_amdgcn_mfma_f32_32x32x16_bf16(A1h[kk], cur.h[kk], acc1, 0, 0, 0);
        acc0 = __builtin_amdgcn_mfma_f32_32x32x16_bf16(A0l[kk], cur.h[kk], acc0, 0, 0, 0);
        acc1 = __builtin_amdgcn_mfma_f32_32x32x16_bf16(A1l[kk], cur.h[kk], acc1, 0, 0, 0);
    }
    if (LN) load_half(Blo, nrown, hi, nxt.l);                     // prefetch Blo(i+1)
#pragma unroll
    for (int kk = 0; kk < 4; ++kk) {           // Bl phase: Ah*Bl
        acc0 = __builtin_amdgcn_mfma_f32_32x32x16_bf16(A0h[kk], cur.l[kk], acc0, 0, 0, 0);
        acc1 = __builtin_amdgcn_mfma_f32_32x32x16_bf16(A1h[kk], cur.l[kk], acc1, 0, 0, 0);
    }

    // store: out row = mb*128 + nbb*4 + I, cols (mt*32+drow_full)*128 + w*32 + l31
    const int rl = nbb * 4 + I;
    float* obase  = out + (((size_t)(mb * 128 + rl)) << 13) + w * 32 + l31 + (size_t)hi * 512;
    float* obase2 = obase + 32 * 128;
#pragma unroll
    for (int r = 0; r < 16; ++r) {
        const int drow = (r & 3) + 8 * (r >> 2);
        __builtin_nontemporal_store(acc0[r], obase  + (size_t)drow * 128);
        __builtin_nontemporal_store(acc1[r], obase2 + (size_t)drow * 128);
    }
}

// grid 2048 = (mb 0..63: m rows [mb*64,+64)) x (nbb 0..31: n [nbb*512,+512)).
// D layout: col=lane&31, row=(reg&3)+8*(reg>>2)+4*(lane>>5)  [verified r4]
__global__ __launch_bounds__(256, 3) void k_out5(const float* __restrict__ ws,
                                                 float* __restrict__ out) {
    const char* wsb = (const char*)ws;
    const unsigned short* Ahi = (const unsigned short*)(wsb + BOFF_AHI);
    const unsigned short* Alo = (const unsigned short*)(wsb + BOFF_ALO);
    const unsigned short* Bhi = (const unsigned short*)(wsb + BOFF_BHI);
    const unsigned short* Blo = (const unsigned short*)(wsb + BOFF_BLO);

    const int tid  = threadIdx.x;
    const int lane = tid & 63;
    const int w    = tid >> 6;          // wave 0..3
    const int mb   = blockIdx.x >> 5;   // 0..63
    const int nbb  = blockIdx.x & 31;   // 0..31
    const int l31  = lane & 31;
    const int hi   = lane >> 5;         // 0/1

    // A fragments: 2 m-tiles x 4 k-steps, hi/lo (row=lane&31, k=kk*16+hi*8+j)
    bf16x8 A0h[4], A0l[4], A1h[4], A1l[4];
    {
        const int m0 = mb * 64 + l31;
        const int m1 = m0 + 32;
#pragma unroll
        for (int kk = 0; kk < 4; ++kk) {
            const int o = kk * 16 + hi * 8;
            A0h[kk] = *(const bf16x8*)(Ahi + m0 * 64 + o);
            A0l[kk] = *(const bf16x8*)(Alo + m0 * 64 + o);
            A1h[kk] = *(const bf16x8*)(Ahi + m1 * 64 + o);
            A1l[kk] = *(const bf16x8*)(Alo + m1 * 64 + o);
        }
    }

    BF b0, b1;
    {
        const int nrow0 = nbb * 512 + w * 32 + l31;   // i=0
        load_half(Bhi, nrow0, hi, b0.h);
        load_half(Blo, nrow0, hi, b0.l);
    }

    tile_iter<0, true >(Bhi, Blo, out, A0h, A0l, A1h, A1l, b0, b1, mb, nbb, w, l31, hi);
    tile_iter<1, true >(Bhi, Blo, out, A0h, A0l, A1h, A1l, b1, b0, mb, nbb, w, l31, hi);
    tile_iter<2, true >(Bhi, Blo, out, A0h, A0l, A1h, A1l, b0, b1, mb, nbb, w, l31, hi);
    tile_iter<3, false>(Bhi, Blo, out, A0h, A0l, A1h, A1l, b1, b0, mb, nbb, w, l31, hi);
}

// ---------------------------------------------------------------------------
extern "C" void kernel_launch(void* const* d_in, const int* in_sizes, int n_in,
                              void* d_out, int out_size, void* d_ws, size_t ws_size,
                              hipStream_t stream) {
    const float* bw    = (const float*)d_in[0];   // (13, 32)
    const float* basis = (const float*)d_in[1];   // (32, 8, 4, 8)
    const float* ra    = (const float*)d_in[2];   // (13, 8)
    float* out = (float*)d_out;                   // (8192, 8192) f32
    float* ws  = (float*)d_ws;

    k_chains<<<64,   256, 0, stream>>>(bw, basis, ra, ws);
    k_build <<<640,  256, 0, stream>>>(ws);
    k_out5  <<<2048, 256, 0, stream>>>(ws, out);
}